// Round 1
// baseline (1137.342 us; speedup 1.0000x reference)
//
#include <hip/hip_runtime.h>
#include <hip/hip_bf16.h>

#define Bsz 4
#define Tsz 2048
#define Hsz 768
#define NHsz 12
#define HDsz 64
#define Msz (Bsz*Tsz)   // 8192

typedef unsigned short u16;
typedef unsigned int u32;

__device__ __forceinline__ float bf2f(u16 u) {
    union { u32 i; float f; } x; x.i = ((u32)u) << 16; return x.f;
}
__device__ __forceinline__ u16 f2bf(float f) {
    union { float f; u32 i; } x; x.f = f;
    u32 i = x.i;
    u32 r = (i + 0x7fffu + ((i >> 16) & 1u)) >> 16;
    return (u16)r;
}

// ---------------------------------------------------------------------------
// Kernel 1: fused QKV projection.  Y = X @ W^T + b  for W in {Wq,Wk,Wv}
// (selected by blockIdx.z).  Output scattered to [b][h][t][d] bf16 layout.
// 64x64 tile, BK=16, 256 threads, 4x4 microtile per thread.
// ---------------------------------------------------------------------------
__global__ __launch_bounds__(256) void qkv_gemm(
    const float* __restrict__ X,
    const float* __restrict__ Wq, const float* __restrict__ bq,
    const float* __restrict__ Wk, const float* __restrict__ bk,
    const float* __restrict__ Wv, const float* __restrict__ bv,
    u16* __restrict__ q_ws, u16* __restrict__ k_ws, u16* __restrict__ v_ws)
{
    const int z = blockIdx.z;
    const float* W    = (z==0) ? Wq : (z==1) ? Wk : Wv;
    const float* bias = (z==0) ? bq : (z==1) ? bk : bv;
    u16* outp         = (z==0) ? q_ws : (z==1) ? k_ws : v_ws;

    __shared__ float As[16][68];   // [k][m], stride 68 -> aligned float4 reads
    __shared__ float Bs[16][68];   // [k][n]

    const int tx = threadIdx.x, ty = threadIdx.y;
    const int tid = ty*16 + tx;
    const int m0 = blockIdx.y * 64;
    const int n0 = blockIdx.x * 64;
    const int lm = tid >> 2;          // 0..63
    const int lk = (tid & 3) << 2;    // 0,4,8,12

    float acc[4][4] = {};

    for (int k0 = 0; k0 < Hsz; k0 += 16) {
        float4 a = *(const float4*)(X + (size_t)(m0+lm)*Hsz + k0 + lk);
        float4 w = *(const float4*)(W + (size_t)(n0+lm)*Hsz + k0 + lk);
        __syncthreads();
        As[lk+0][lm]=a.x; As[lk+1][lm]=a.y; As[lk+2][lm]=a.z; As[lk+3][lm]=a.w;
        Bs[lk+0][lm]=w.x; Bs[lk+1][lm]=w.y; Bs[lk+2][lm]=w.z; Bs[lk+3][lm]=w.w;
        __syncthreads();
        #pragma unroll
        for (int kk = 0; kk < 16; ++kk) {
            float4 av = *(const float4*)(&As[kk][ty<<2]);
            float4 bv4 = *(const float4*)(&Bs[kk][tx<<2]);
            float aa[4] = {av.x, av.y, av.z, av.w};
            float bb[4] = {bv4.x, bv4.y, bv4.z, bv4.w};
            #pragma unroll
            for (int i=0;i<4;++i)
                #pragma unroll
                for (int j=0;j<4;++j)
                    acc[i][j] += aa[i]*bb[j];
        }
    }

    #pragma unroll
    for (int i=0;i<4;++i) {
        int m = m0 + (ty<<2) + i;
        int bi = m >> 11;          // /T
        int t  = m & (Tsz-1);      // %T
        #pragma unroll
        for (int j=0;j<4;++j) {
            int n = n0 + (tx<<2) + j;
            int h = n >> 6, d = n & 63;
            outp[(((size_t)(bi*NHsz + h)*Tsz + t)*HDsz) + d] = f2bf(acc[i][j] + bias[n]);
        }
    }
}

// ---------------------------------------------------------------------------
// Kernel 2: causal flash attention, fp32 compute, bf16 q/k/v input.
// One block per (b, h, 64-row Q tile).  256 threads, 4x4 microtile.
// Online softmax; only processes qtile+1 KV tiles (causal skip).
// ---------------------------------------------------------------------------
__global__ __launch_bounds__(256) void attn(
    const u16* __restrict__ q_ws, const u16* __restrict__ k_ws,
    const u16* __restrict__ v_ws, const float* __restrict__ am,
    float* __restrict__ out)
{
    const int qt = blockIdx.x, h = blockIdx.y, b = blockIdx.z;

    __shared__ float Qs[64][68];   // [d][i]
    __shared__ float KVs[64][68];  // K phase: [d][j]; V phase: [j][d]
    __shared__ float Ps[64][68];   // [j][i]

    const int tx = threadIdx.x, ty = threadIdx.y;
    const int tid = ty*16 + tx;
    const int qr0 = qt*64;
    const size_t base = ((size_t)(b*NHsz + h))*Tsz*HDsz;
    const u16* Qb = q_ws + base;
    const u16* Kb = k_ws + base;
    const u16* Vb = v_ws + base;
    const float* amb = am + (size_t)b*Tsz;

    // Load Q tile (64x64 bf16), transpose into Qs[d][i]
    #pragma unroll
    for (int rep=0; rep<2; ++rep) {
        int f = tid + rep*256;       // 0..511 chunks of 8 bf16
        int r = f >> 3;              // 0..63
        int dc = (f & 7) << 3;       // 0..56
        uint4 pk = *(const uint4*)(Qb + (size_t)(qr0 + r)*HDsz + dc);
        u32 ww[4] = {pk.x, pk.y, pk.z, pk.w};
        #pragma unroll
        for (int e=0; e<4; ++e) {
            Qs[dc + 2*e + 0][r] = bf2f((u16)(ww[e] & 0xffffu));
            Qs[dc + 2*e + 1][r] = bf2f((u16)(ww[e] >> 16));
        }
    }

    float o[4][4] = {};
    float mrow[4] = {-INFINITY,-INFINITY,-INFINITY,-INFINITY};
    float lrow[4] = {0.f,0.f,0.f,0.f};

    const int qi0 = qr0 + (ty<<2);
    const int ntiles = qt + 1;

    for (int kt = 0; kt < ntiles; ++kt) {
        const int kv0 = kt*64;
        __syncthreads();   // prev PV done before overwriting KVs; Qs/Ps safe
        // K tile -> KVs[d][j] (transposed)
        #pragma unroll
        for (int rep=0; rep<2; ++rep) {
            int f = tid + rep*256;
            int r = f >> 3;
            int dc = (f & 7) << 3;
            uint4 pk = *(const uint4*)(Kb + (size_t)(kv0 + r)*HDsz + dc);
            u32 ww[4] = {pk.x, pk.y, pk.z, pk.w};
            #pragma unroll
            for (int e=0; e<4; ++e) {
                KVs[dc + 2*e + 0][r] = bf2f((u16)(ww[e] & 0xffffu));
                KVs[dc + 2*e + 1][r] = bf2f((u16)(ww[e] >> 16));
            }
        }
        __syncthreads();

        // S = Q @ K^T (reduce over d)
        float s[4][4] = {};
        #pragma unroll 4
        for (int d=0; d<64; ++d) {
            float4 av = *(const float4*)(&Qs[d][ty<<2]);
            float4 kv = *(const float4*)(&KVs[d][tx<<2]);
            float aa[4] = {av.x, av.y, av.z, av.w};
            float kk[4] = {kv.x, kv.y, kv.z, kv.w};
            #pragma unroll
            for (int i=0;i<4;++i)
                #pragma unroll
                for (int j=0;j<4;++j)
                    s[i][j] += aa[i]*kk[j];
        }

        // scale + causal mask + attention mask
        const int kj0 = kv0 + (tx<<2);
        float amv[4];
        #pragma unroll
        for (int j=0;j<4;++j) amv[j] = amb[kj0+j];
        #pragma unroll
        for (int i=0;i<4;++i) {
            int qi = qi0 + i;
            #pragma unroll
            for (int j=0;j<4;++j) {
                float val = ((kj0+j) > qi) ? -1e9f : s[i][j]*0.125f;
                s[i][j] = val + amv[j];
            }
        }

        // row max across this thread's 4 cols, then across the 16 tx lanes
        float mx[4];
        #pragma unroll
        for (int i=0;i<4;++i)
            mx[i] = fmaxf(fmaxf(s[i][0],s[i][1]), fmaxf(s[i][2],s[i][3]));
        #pragma unroll
        for (int d2=1; d2<16; d2<<=1) {
            #pragma unroll
            for (int i=0;i<4;++i)
                mx[i] = fmaxf(mx[i], __shfl_xor(mx[i], d2, 16));
        }

        // online softmax update
        float p[4][4];
        float psum[4];
        #pragma unroll
        for (int i=0;i<4;++i) {
            float mnew = fmaxf(mrow[i], mx[i]);
            float corr = expf(mrow[i] - mnew);
            mrow[i] = mnew;
            float ps = 0.f;
            #pragma unroll
            for (int j=0;j<4;++j) {
                float pv = expf(s[i][j] - mnew);
                p[i][j] = pv;
                ps += pv;
            }
            psum[i] = ps;
            lrow[i] *= corr;
            #pragma unroll
            for (int d=0;d<4;++d) o[i][d] *= corr;
        }
        #pragma unroll
        for (int d2=1; d2<16; d2<<=1) {
            #pragma unroll
            for (int i=0;i<4;++i)
                psum[i] += __shfl_xor(psum[i], d2, 16);
        }
        #pragma unroll
        for (int i=0;i<4;++i) lrow[i] += psum[i];

        // write P transposed: Ps[j][i]
        #pragma unroll
        for (int j=0;j<4;++j) {
            float4 w4 = make_float4(p[0][j], p[1][j], p[2][j], p[3][j]);
            *(float4*)(&Ps[(tx<<2)+j][ty<<2]) = w4;
        }
        __syncthreads();   // Ps written; all done reading KVs as K

        // V tile -> KVs[j][d] (direct layout)
        #pragma unroll
        for (int rep=0; rep<2; ++rep) {
            int f = tid + rep*256;
            int r = f >> 3;
            int dc = (f & 7) << 3;
            uint4 pk = *(const uint4*)(Vb + (size_t)(kv0 + r)*HDsz + dc);
            u32 ww[4] = {pk.x, pk.y, pk.z, pk.w};
            float fv[8];
            #pragma unroll
            for (int e=0; e<4; ++e) {
                fv[2*e+0] = bf2f((u16)(ww[e] & 0xffffu));
                fv[2*e+1] = bf2f((u16)(ww[e] >> 16));
            }
            *(float4*)(&KVs[r][dc])   = make_float4(fv[0],fv[1],fv[2],fv[3]);
            *(float4*)(&KVs[r][dc+4]) = make_float4(fv[4],fv[5],fv[6],fv[7]);
        }
        __syncthreads();

        // O += P @ V (reduce over j)
        #pragma unroll 4
        for (int j=0; j<64; ++j) {
            float4 pv4 = *(const float4*)(&Ps[j][ty<<2]);
            float4 vv4 = *(const float4*)(&KVs[j][tx<<2]);
            float pp[4] = {pv4.x, pv4.y, pv4.z, pv4.w};
            float vv[4] = {vv4.x, vv4.y, vv4.z, vv4.w};
            #pragma unroll
            for (int i=0;i<4;++i)
                #pragma unroll
                for (int d=0;d<4;++d)
                    o[i][d] += pp[i]*vv[d];
        }
    }

    // epilogue: normalize, write out[b][t][h*64+d]
    #pragma unroll
    for (int i=0;i<4;++i) {
        int t = qr0 + (ty<<2) + i;
        float inv = 1.0f / lrow[i];
        float4 r4 = make_float4(o[i][0]*inv, o[i][1]*inv, o[i][2]*inv, o[i][3]*inv);
        *(float4*)(out + ((size_t)(b*Tsz + t))*Hsz + h*HDsz + (tx<<2)) = r4;
    }
}

extern "C" void kernel_launch(void* const* d_in, const int* in_sizes, int n_in,
                              void* d_out, int out_size, void* d_ws, size_t ws_size,
                              hipStream_t stream) {
    const float* X  = (const float*)d_in[0];
    const float* am = (const float*)d_in[1];
    const float* Wq = (const float*)d_in[2];
    const float* bq = (const float*)d_in[3];
    const float* Wk = (const float*)d_in[4];
    const float* bk = (const float*)d_in[5];
    const float* Wv = (const float*)d_in[6];
    const float* bv = (const float*)d_in[7];
    float* out = (float*)d_out;

    const size_t per = (size_t)Msz * Hsz;   // 6,291,456 bf16 elems each
    u16* q_ws = (u16*)d_ws;
    u16* k_ws = q_ws + per;
    u16* v_ws = k_ws + per;

    dim3 b1(16,16);
    dim3 g1(Hsz/64, Msz/64, 3);             // (12, 128, 3)
    qkv_gemm<<<g1, b1, 0, stream>>>(X, Wq,bq, Wk,bk, Wv,bv, q_ws, k_ws, v_ws);

    dim3 g2(Tsz/64, NHsz, Bsz);             // (32, 12, 4)
    attn<<<g2, b1, 0, stream>>>(q_ws, k_ws, v_ws, am, out);
}

// Round 4
// 284.264 us; speedup vs baseline: 4.0010x; 4.0010x over previous
//
#include <hip/hip_runtime.h>
#include <hip/hip_bf16.h>

#define Tsz 2048
#define Hsz 768
#define NHsz 12
#define HDsz 64

typedef unsigned short u16;
typedef unsigned int u32;
typedef __attribute__((ext_vector_type(8))) short bf16x8;
typedef __attribute__((ext_vector_type(4))) float f32x4;

__device__ __forceinline__ u16 f2bf(float f) {
    union { float f; u32 i; } x; x.f = f;
    u32 i = x.i;
    u32 r = (i + 0x7fffu + ((i >> 16) & 1u)) >> 16;
    return (u16)r;
}

__device__ __forceinline__ void glds16(const u16* src, u16* ldsbase) {
    __builtin_amdgcn_global_load_lds(
        (const __attribute__((address_space(1))) u32*)src,
        (__attribute__((address_space(3))) u32*)ldsbase, 16, 0, 0);
}

// read a bf16x8 MFMA fragment chunk c (16B units) of row `row` from a
// [rows][64] bf16 LDS tile stored with chunk-XOR swizzle (chunk ^= row&7)
#define LDSFRAG(base, row, c) \
    (*(const bf16x8*)((const char*)(base) + (row)*128 + ((((c) << 4)) ^ (((row) & 7) << 4))))

// ---------------------------------------------------------------------------
// Kernel 1: QKV projection with MFMA.  Y = X @ W^T + b.
// Block tile 128m x 128n, BK=64, 4 waves each 64x64.
// q,k written [b][h][t][d] bf16; v written TRANSPOSED [b][h][d][t] bf16.
// ---------------------------------------------------------------------------
__global__ __launch_bounds__(256) void qkv_mfma(
    const float* __restrict__ X,
    const float* __restrict__ Wq, const float* __restrict__ bq,
    const float* __restrict__ Wk, const float* __restrict__ bk,
    const float* __restrict__ Wv, const float* __restrict__ bv,
    u16* __restrict__ q_ws, u16* __restrict__ k_ws, u16* __restrict__ vt_ws)
{
    const int tid = threadIdx.x;
    const int w = tid >> 6, l = tid & 63, lg = l >> 4, lh = l & 15;
    const int m0 = blockIdx.x * 128;
    const int nb = blockIdx.y;            // 0..17 over 3*768 columns
    const int z = nb / 6;
    const int n0l = (nb % 6) * 128;       // column base within this W
    const float* W    = (z == 0) ? Wq : (z == 1) ? Wk : Wv;
    const float* bias = (z == 0) ? bq : (z == 1) ? bk : bv;

    __shared__ __align__(16) u16 Xs[128 * 64];
    __shared__ __align__(16) u16 Ws[128 * 64];

    const int wm = w >> 1, wn = w & 1;

    f32x4 acc[4][4];
    #pragma unroll
    for (int i = 0; i < 4; ++i)
        #pragma unroll
        for (int j = 0; j < 4; ++j)
            acc[i][j] = (f32x4){0.f, 0.f, 0.f, 0.f};

    for (int k0 = 0; k0 < Hsz; k0 += 64) {
        __syncthreads();   // previous compute done; LDS free
        #pragma unroll
        for (int p = 0; p < 4; ++p) {
            int id = tid + p * 256;       // 0..1023 chunks of 8 elems
            int r = id >> 3, c8 = id & 7;
            int cswz = c8 ^ (r & 7);
            // X chunk
            float4 xa = *(const float4*)(X + (size_t)(m0 + r) * Hsz + k0 + c8 * 8);
            float4 xb = *(const float4*)(X + (size_t)(m0 + r) * Hsz + k0 + c8 * 8 + 4);
            bf16x8 xv;
            xv[0] = (short)f2bf(xa.x); xv[1] = (short)f2bf(xa.y);
            xv[2] = (short)f2bf(xa.z); xv[3] = (short)f2bf(xa.w);
            xv[4] = (short)f2bf(xb.x); xv[5] = (short)f2bf(xb.y);
            xv[6] = (short)f2bf(xb.z); xv[7] = (short)f2bf(xb.w);
            *(bf16x8*)((char*)Xs + r * 128 + cswz * 16) = xv;
            // W chunk
            float4 wa = *(const float4*)(W + (size_t)(n0l + r) * Hsz + k0 + c8 * 8);
            float4 wb = *(const float4*)(W + (size_t)(n0l + r) * Hsz + k0 + c8 * 8 + 4);
            bf16x8 wv8;
            wv8[0] = (short)f2bf(wa.x); wv8[1] = (short)f2bf(wa.y);
            wv8[2] = (short)f2bf(wa.z); wv8[3] = (short)f2bf(wa.w);
            wv8[4] = (short)f2bf(wb.x); wv8[5] = (short)f2bf(wb.y);
            wv8[6] = (short)f2bf(wb.z); wv8[7] = (short)f2bf(wb.w);
            *(bf16x8*)((char*)Ws + r * 128 + cswz * 16) = wv8;
        }
        __syncthreads();
        #pragma unroll
        for (int s = 0; s < 2; ++s) {
            bf16x8 af[4], bfr[4];
            #pragma unroll
            for (int tq = 0; tq < 4; ++tq) {
                af[tq]  = LDSFRAG(Xs, wm * 64 + tq * 16 + lh, 4 * s + lg);
                bfr[tq] = LDSFRAG(Ws, wn * 64 + tq * 16 + lh, 4 * s + lg);
            }
            #pragma unroll
            for (int mt = 0; mt < 4; ++mt)
                #pragma unroll
                for (int nt = 0; nt < 4; ++nt)
                    acc[mt][nt] = __builtin_amdgcn_mfma_f32_16x16x32_bf16(
                        af[mt], bfr[nt], acc[mt][nt], 0, 0, 0);
        }
    }

    // epilogue: scatter to q/k ([bh][t][d]) or v transposed ([bh][d][t])
    #pragma unroll
    for (int nt = 0; nt < 4; ++nt) {
        int nloc = n0l + wn * 64 + nt * 16 + lh;   // 0..767
        float bval = bias[nloc];
        int hh = nloc >> 6, d = nloc & 63;
        #pragma unroll
        for (int mt = 0; mt < 4; ++mt) {
            #pragma unroll
            for (int r = 0; r < 4; ++r) {
                int m = m0 + wm * 64 + mt * 16 + lg * 4 + r;
                int bb = m >> 11, t = m & 2047;
                u16 val = f2bf(acc[mt][nt][r] + bval);
                size_t bh = (size_t)(bb * NHsz + hh);
                if (z == 0)      q_ws[(bh * Tsz + t) * HDsz + d] = val;
                else if (z == 1) k_ws[(bh * Tsz + t) * HDsz + d] = val;
                else             vt_ws[(bh * HDsz + d) * Tsz + t] = val;
            }
        }
    }
}

// ---------------------------------------------------------------------------
// Kernel 2: causal flash attention with MFMA.
// Block = (b, h, 64-row Q tile); 4 waves, each owns 16 q-rows.
// K/V tiles staged via global_load_lds with pre-swizzled source (linear LDS,
// XOR-swizzled contents). P round-trips through wave-private padded LDS.
// ---------------------------------------------------------------------------
__global__ __launch_bounds__(256) void attn_mfma(
    const u16* __restrict__ q_ws, const u16* __restrict__ k_ws,
    const u16* __restrict__ vt_ws, const float* __restrict__ am,
    float* __restrict__ out)
{
    const int tid = threadIdx.x;
    const int w = tid >> 6, l = tid & 63, lg = l >> 4, lh = l & 15;
    const int qt = (int)gridDim.x - 1 - (int)blockIdx.x;   // longest first
    const int h = blockIdx.y, b = blockIdx.z;
    const int bh = b * NHsz + h;

    const u16* Qb = q_ws + (size_t)bh * Tsz * HDsz;
    const u16* Kb = k_ws + (size_t)bh * Tsz * HDsz;
    const u16* Vb = vt_ws + (size_t)bh * HDsz * Tsz;   // [d][t]
    const float* amb = am + (size_t)b * Tsz;

    __shared__ __align__(16) u16 Ks[64 * 64];
    __shared__ __align__(16) u16 Vs[64 * 64];          // [d][kv] layout
    __shared__ __align__(16) u16 Ps[4][16][72];

    const int q0 = qt * 64 + w * 16;
    const int prow = lg * 4;

    bf16x8 qf0 = *(const bf16x8*)(Qb + (size_t)(q0 + lh) * HDsz + lg * 8);
    bf16x8 qf1 = *(const bf16x8*)(Qb + (size_t)(q0 + lh) * HDsz + lg * 8 + 32);

    f32x4 o0 = {0,0,0,0}, o1 = {0,0,0,0}, o2 = {0,0,0,0}, o3 = {0,0,0,0};
    float m2[4], l2[4];
    #pragma unroll
    for (int r = 0; r < 4; ++r) { m2[r] = -1e30f; l2[r] = 0.f; }

    const float SCALE2 = 0.125f * 1.44269504f;
    const float LOG2E  = 1.44269504f;
    const f32x4 zero4 = {0,0,0,0};
    u16* myP = &Ps[w][0][0];

    for (int kt = 0; kt <= qt; ++kt) {
        const int kv0 = kt * 64;
        const bool diag = (kt == qt);
        const int nmax = diag ? w : 3;

        __syncthreads();   // previous tile's LDS reads done
        #pragma unroll
        for (int p = 0; p < 2; ++p) {
            int id = w * 128 + p * 64 + l;
            int r = id >> 3, c8 = id & 7;
            int cswz = c8 ^ (r & 7);     // pre-swizzled source, linear LDS
            glds16(Kb + (size_t)(kv0 + r) * HDsz + cswz * 8,
                   Ks + (w * 128 + p * 64) * 8);
            glds16(Vb + (size_t)r * Tsz + kv0 + cswz * 8,
                   Vs + (w * 128 + p * 64) * 8);
        }
        __syncthreads();   // staged data visible (vmcnt drained at barrier)

        // ---- S = Q K^T ----
        f32x4 sarr[4] = {zero4, zero4, zero4, zero4};
        #pragma unroll
        for (int n = 0; n < 4; ++n) {
            if (n <= nmax) {
                int row = n * 16 + lh;
                bf16x8 kf0 = LDSFRAG(Ks, row, lg);
                bf16x8 kf1 = LDSFRAG(Ks, row, 4 + lg);
                f32x4 c = __builtin_amdgcn_mfma_f32_16x16x32_bf16(qf0, kf0, zero4, 0, 0, 0);
                c = __builtin_amdgcn_mfma_f32_16x16x32_bf16(qf1, kf1, c, 0, 0, 0);
                sarr[n] = c;
            }
        }

        // ---- softmax (log2 domain) ----
        float pv[4][4];
        float mx[4] = {-1e30f, -1e30f, -1e30f, -1e30f};
        #pragma unroll
        for (int n = 0; n < 4; ++n) {
            if (n <= nmax) {
                int kvj = kv0 + n * 16 + lh;
                float a2 = amb[kvj] * LOG2E;
                #pragma unroll
                for (int r = 0; r < 4; ++r) {
                    int qrow = q0 + prow + r;
                    float sv = (kvj > qrow) ? -1e30f : sarr[n][r] * SCALE2 + a2;
                    pv[n][r] = sv;
                    mx[r] = fmaxf(mx[r], sv);
                }
            } else {
                #pragma unroll
                for (int r = 0; r < 4; ++r) pv[n][r] = -1e30f;
            }
        }
        #pragma unroll
        for (int d2 = 1; d2 < 16; d2 <<= 1)
            #pragma unroll
            for (int r = 0; r < 4; ++r)
                mx[r] = fmaxf(mx[r], __shfl_xor(mx[r], d2));

        float corr[4], psum[4];
        #pragma unroll
        for (int r = 0; r < 4; ++r) {
            float mn = fmaxf(m2[r], mx[r]);
            corr[r] = exp2f(m2[r] - mn);
            m2[r] = mn;
            psum[r] = 0.f;
        }
        #pragma unroll
        for (int n = 0; n < 4; ++n)
            #pragma unroll
            for (int r = 0; r < 4; ++r) {
                float p = exp2f(pv[n][r] - m2[r]);
                pv[n][r] = p;
                psum[r] += p;
            }

        // write P (bf16) to wave-private LDS
        #pragma unroll
        for (int n = 0; n < 4; ++n)
            #pragma unroll
            for (int r = 0; r < 4; ++r)
                myP[(prow + r) * 72 + n * 16 + lh] = f2bf(pv[n][r]);

        #pragma unroll
        for (int d2 = 1; d2 < 16; d2 <<= 1)
            #pragma unroll
            for (int r = 0; r < 4; ++r)
                psum[r] += __shfl_xor(psum[r], d2);

        #pragma unroll
        for (int r = 0; r < 4; ++r) {
            l2[r] = l2[r] * corr[r] + psum[r];
            o0[r] *= corr[r]; o1[r] *= corr[r];
            o2[r] *= corr[r]; o3[r] *= corr[r];
        }

        // ---- O += P V ----
        const int smax = (diag && w < 2) ? 0 : 1;
        #pragma unroll
        for (int s = 0; s < 2; ++s) {
            if (s > smax) continue;
            bf16x8 pf = *(const bf16x8*)((const char*)myP + lh * 144 + lg * 16 + s * 64);
            bf16x8 v0 = LDSFRAG(Vs, 0 * 16 + lh, 4 * s + lg);
            bf16x8 v1 = LDSFRAG(Vs, 1 * 16 + lh, 4 * s + lg);
            bf16x8 v2 = LDSFRAG(Vs, 2 * 16 + lh, 4 * s + lg);
            bf16x8 v3 = LDSFRAG(Vs, 3 * 16 + lh, 4 * s + lg);
            o0 = __builtin_amdgcn_mfma_f32_16x16x32_bf16(pf, v0, o0, 0, 0, 0);
            o1 = __builtin_amdgcn_mfma_f32_16x16x32_bf16(pf, v1, o1, 0, 0, 0);
            o2 = __builtin_amdgcn_mfma_f32_16x16x32_bf16(pf, v2, o2, 0, 0, 0);
            o3 = __builtin_amdgcn_mfma_f32_16x16x32_bf16(pf, v3, o3, 0, 0, 0);
        }
    }

    // epilogue: out[b][t][h*64+d] fp32
    float* ob = out + ((size_t)(b * Tsz + q0 + prow)) * Hsz + h * HDsz + lh;
    #pragma unroll
    for (int r = 0; r < 4; ++r) {
        float inv = 1.0f / l2[r];
        ob[r * Hsz + 0]  = o0[r] * inv;
        ob[r * Hsz + 16] = o1[r] * inv;
        ob[r * Hsz + 32] = o2[r] * inv;
        ob[r * Hsz + 48] = o3[r] * inv;
    }
}

extern "C" void kernel_launch(void* const* d_in, const int* in_sizes, int n_in,
                              void* d_out, int out_size, void* d_ws, size_t ws_size,
                              hipStream_t stream) {
    const float* X  = (const float*)d_in[0];
    const float* am = (const float*)d_in[1];
    const float* Wq = (const float*)d_in[2];
    const float* bq = (const float*)d_in[3];
    const float* Wk = (const float*)d_in[4];
    const float* bk = (const float*)d_in[5];
    const float* Wv = (const float*)d_in[6];
    const float* bv = (const float*)d_in[7];
    float* out = (float*)d_out;

    const size_t per = (size_t)8192 * Hsz;   // 6,291,456 bf16 elems
    u16* q_ws  = (u16*)d_ws;
    u16* k_ws  = q_ws + per;
    u16* vt_ws = k_ws + per;

    dim3 g1(64, 18);
    qkv_mfma<<<g1, 256, 0, stream>>>(X, Wq, bq, Wk, bk, Wv, bv, q_ws, k_ws, vt_ws);

    dim3 g2(32, NHsz, 4);
    attn_mfma<<<g2, 256, 0, stream>>>(q_ws, k_ws, vt_ws, am, out);
}

// Round 5
// 252.221 us; speedup vs baseline: 4.5093x; 1.1270x over previous
//
#include <hip/hip_runtime.h>
#include <hip/hip_bf16.h>

#define Tsz 2048
#define Hsz 768
#define NHsz 12
#define HDsz 64

typedef unsigned short u16;
typedef unsigned int u32;
typedef __attribute__((ext_vector_type(8))) short bf16x8;
typedef __attribute__((ext_vector_type(4))) float f32x4;
typedef __attribute__((ext_vector_type(4))) u16 u16x4;

__device__ __forceinline__ u16 f2bf(float f) {
    union { float f; u32 i; } x; x.f = f;
    u32 i = x.i;
    u32 r = (i + 0x7fffu + ((i >> 16) & 1u)) >> 16;
    return (u16)r;
}

__device__ __forceinline__ void glds16(const void* src, void* ldsbase) {
    __builtin_amdgcn_global_load_lds(
        (const __attribute__((address_space(1))) u32*)src,
        (__attribute__((address_space(3))) u32*)ldsbase, 16, 0, 0);
}

#define BAR() do { asm volatile("" ::: "memory"); \
                   __builtin_amdgcn_s_barrier();  \
                   asm volatile("" ::: "memory"); } while (0)

// read a bf16x8 MFMA fragment chunk c (16B units) of row `row` from a
// [rows][64] bf16 LDS tile stored with chunk-XOR swizzle (chunk ^= row&7)
#define LDSFRAG(base, row, c) \
    (*(const bf16x8*)((const char*)(base) + (row)*128 + ((((c) << 4)) ^ (((row) & 7) << 4))))

// ---------------------------------------------------------------------------
// Kernel 1: QKV projection with MFMA (unchanged from round 4).
// ---------------------------------------------------------------------------
__global__ __launch_bounds__(256) void qkv_mfma(
    const float* __restrict__ X,
    const float* __restrict__ Wq, const float* __restrict__ bq,
    const float* __restrict__ Wk, const float* __restrict__ bk,
    const float* __restrict__ Wv, const float* __restrict__ bv,
    u16* __restrict__ q_ws, u16* __restrict__ k_ws, u16* __restrict__ vt_ws)
{
    const int tid = threadIdx.x;
    const int w = tid >> 6, l = tid & 63, lg = l >> 4, lh = l & 15;
    const int m0 = blockIdx.x * 128;
    const int nb = blockIdx.y;
    const int z = nb / 6;
    const int n0l = (nb % 6) * 128;
    const float* W    = (z == 0) ? Wq : (z == 1) ? Wk : Wv;
    const float* bias = (z == 0) ? bq : (z == 1) ? bk : bv;

    __shared__ __align__(16) u16 Xs[128 * 64];
    __shared__ __align__(16) u16 Ws[128 * 64];

    const int wm = w >> 1, wn = w & 1;

    f32x4 acc[4][4];
    #pragma unroll
    for (int i = 0; i < 4; ++i)
        #pragma unroll
        for (int j = 0; j < 4; ++j)
            acc[i][j] = (f32x4){0.f, 0.f, 0.f, 0.f};

    for (int k0 = 0; k0 < Hsz; k0 += 64) {
        __syncthreads();
        #pragma unroll
        for (int p = 0; p < 4; ++p) {
            int id = tid + p * 256;
            int r = id >> 3, c8 = id & 7;
            int cswz = c8 ^ (r & 7);
            float4 xa = *(const float4*)(X + (size_t)(m0 + r) * Hsz + k0 + c8 * 8);
            float4 xb = *(const float4*)(X + (size_t)(m0 + r) * Hsz + k0 + c8 * 8 + 4);
            bf16x8 xv;
            xv[0] = (short)f2bf(xa.x); xv[1] = (short)f2bf(xa.y);
            xv[2] = (short)f2bf(xa.z); xv[3] = (short)f2bf(xa.w);
            xv[4] = (short)f2bf(xb.x); xv[5] = (short)f2bf(xb.y);
            xv[6] = (short)f2bf(xb.z); xv[7] = (short)f2bf(xb.w);
            *(bf16x8*)((char*)Xs + r * 128 + cswz * 16) = xv;
            float4 wa = *(const float4*)(W + (size_t)(n0l + r) * Hsz + k0 + c8 * 8);
            float4 wb = *(const float4*)(W + (size_t)(n0l + r) * Hsz + k0 + c8 * 8 + 4);
            bf16x8 wv8;
            wv8[0] = (short)f2bf(wa.x); wv8[1] = (short)f2bf(wa.y);
            wv8[2] = (short)f2bf(wa.z); wv8[3] = (short)f2bf(wa.w);
            wv8[4] = (short)f2bf(wb.x); wv8[5] = (short)f2bf(wb.y);
            wv8[6] = (short)f2bf(wb.z); wv8[7] = (short)f2bf(wb.w);
            *(bf16x8*)((char*)Ws + r * 128 + cswz * 16) = wv8;
        }
        __syncthreads();
        #pragma unroll
        for (int s = 0; s < 2; ++s) {
            bf16x8 af[4], bfr[4];
            #pragma unroll
            for (int tq = 0; tq < 4; ++tq) {
                af[tq]  = LDSFRAG(Xs, wm * 64 + tq * 16 + lh, 4 * s + lg);
                bfr[tq] = LDSFRAG(Ws, wn * 64 + tq * 16 + lh, 4 * s + lg);
            }
            #pragma unroll
            for (int mt = 0; mt < 4; ++mt)
                #pragma unroll
                for (int nt = 0; nt < 4; ++nt)
                    acc[mt][nt] = __builtin_amdgcn_mfma_f32_16x16x32_bf16(
                        af[mt], bfr[nt], acc[mt][nt], 0, 0, 0);
        }
    }

    #pragma unroll
    for (int nt = 0; nt < 4; ++nt) {
        int nloc = n0l + wn * 64 + nt * 16 + lh;
        float bval = bias[nloc];
        int hh = nloc >> 6, d = nloc & 63;
        #pragma unroll
        for (int mt = 0; mt < 4; ++mt) {
            #pragma unroll
            for (int r = 0; r < 4; ++r) {
                int m = m0 + wm * 64 + mt * 16 + lg * 4 + r;
                int bb = m >> 11, t = m & 2047;
                u16 val = f2bf(acc[mt][nt][r] + bval);
                size_t bh = (size_t)(bb * NHsz + hh);
                if (z == 0)      q_ws[(bh * Tsz + t) * HDsz + d] = val;
                else if (z == 1) k_ws[(bh * Tsz + t) * HDsz + d] = val;
                else             vt_ws[(bh * HDsz + d) * Tsz + t] = val;
            }
        }
    }
}

// ---------------------------------------------------------------------------
// Kernel 2: causal flash attention, swapped QK^T + double-buffered staging.
// Block = (b, h, 64-row Q tile); 4 waves, wave w owns q rows [w*16, w*16+16).
// S^T = mfma(K,Q): lane holds S[q=lane&15][16 kv values in-reg] -> in-lane
// softmax (2 shuffles per reduction). P: 4x ds_write_b64 -> 2x ds_read_b128.
// K/V double-buffered: prefetch tile t+1 with counted vmcnt(4), raw barriers.
// ---------------------------------------------------------------------------
__global__ __launch_bounds__(256) void attn_mfma(
    const u16* __restrict__ q_ws, const u16* __restrict__ k_ws,
    const u16* __restrict__ vt_ws, const float* __restrict__ am,
    float* __restrict__ out)
{
    const int tid = threadIdx.x;
    const int w = tid >> 6, l = tid & 63, lg = l >> 4, lh = l & 15;
    const int qt = (int)gridDim.x - 1 - (int)blockIdx.x;   // longest first
    const int h = blockIdx.y, b = blockIdx.z;
    const int bh = b * NHsz + h;

    const u16* Qb = q_ws + (size_t)bh * Tsz * HDsz;
    const u16* Kb = k_ws + (size_t)bh * Tsz * HDsz;
    const u16* Vb = vt_ws + (size_t)bh * HDsz * Tsz;   // [d][t]
    const float* amb = am + (size_t)b * Tsz;

    __shared__ __align__(16) u16 Ks[2][64 * 64];
    __shared__ __align__(16) u16 Vs[2][64 * 64];       // [d][kv] layout
    __shared__ __align__(16) u16 Ps[4][16 * 64];       // per-wave, swizzled
    __shared__ __align__(16) float ambs[Tsz];

    const int q0 = qt * 64 + w * 16;
    const int qrow = q0 + lh;

    // Q fragments (B-operand): lane holds Q[q0+lh][d = lg*8 + j]
    bf16x8 qf0 = *(const bf16x8*)(Qb + (size_t)(q0 + lh) * HDsz + lg * 8);
    bf16x8 qf1 = *(const bf16x8*)(Qb + (size_t)(q0 + lh) * HDsz + lg * 8 + 32);

    // ---- prologue staging: attention mask (8KB) + tile 0 K/V ----
    #pragma unroll
    for (int i = 0; i < 2; ++i)
        glds16(amb + (size_t)(i * 256 + tid) * 4, ambs + (i * 256 + w * 64) * 4);
    #pragma unroll
    for (int p = 0; p < 2; ++p) {
        int id = w * 128 + p * 64 + l;
        int r = id >> 3, c8 = id & 7;
        int cswz = c8 ^ (r & 7);
        glds16(Kb + (size_t)r * HDsz + cswz * 8, &Ks[0][(w * 128 + p * 64) * 8]);
        glds16(Vb + (size_t)r * Tsz + 0 + cswz * 8, &Vs[0][(w * 128 + p * 64) * 8]);
    }
    asm volatile("s_waitcnt vmcnt(0)" ::: "memory");
    BAR();

    f32x4 o[4];
    #pragma unroll
    for (int n = 0; n < 4; ++n) o[n] = (f32x4){0.f, 0.f, 0.f, 0.f};
    float m2 = -1e30f, l2 = 0.f;

    const float LOG2E  = 1.44269504f;
    const float SCALE2 = 0.125f * 1.44269504f;
    const f32x4 zero4 = {0.f, 0.f, 0.f, 0.f};
    u16* myP = &Ps[w][0];
    const int srcbase = l & 0x30;         // own lg group
    const int qo = ((l >> 4) & 3) * 4;    // O-register q rows base

    for (int kt = 0; kt <= qt; ++kt) {
        const int cur = kt & 1;
        const int kv0 = kt * 64;

        if (kt < qt) {
            // prefetch tile kt+1 into the other buffer
            const int kv1 = kv0 + 64;
            #pragma unroll
            for (int p = 0; p < 2; ++p) {
                int id = w * 128 + p * 64 + l;
                int r = id >> 3, c8 = id & 7;
                int cswz = c8 ^ (r & 7);
                glds16(Kb + (size_t)(kv1 + r) * HDsz + cswz * 8,
                       &Ks[cur ^ 1][(w * 128 + p * 64) * 8]);
                glds16(Vb + (size_t)r * Tsz + kv1 + cswz * 8,
                       &Vs[cur ^ 1][(w * 128 + p * 64) * 8]);
            }
            asm volatile("s_waitcnt vmcnt(4)" ::: "memory");
        } else {
            asm volatile("s_waitcnt vmcnt(0)" ::: "memory");
        }
        BAR();   // tile kt fully staged (all waves)

        const u16* Ksb = &Ks[cur][0];
        const u16* Vsb = &Vs[cur][0];
        const bool diag = (kt == qt);
        const int nmax = diag ? w : 3;

        // ---- S^T = K @ Q^T : lane holds S[q=lh][kv = kv0 + n*16 + lg*4 + r]
        f32x4 st[4];
        #pragma unroll
        for (int n = 0; n < 4; ++n) {
            st[n] = zero4;
            if (n <= nmax) {
                int row = n * 16 + lh;
                bf16x8 kf0 = LDSFRAG(Ksb, row, lg);
                bf16x8 kf1 = LDSFRAG(Ksb, row, 4 + lg);
                f32x4 c = __builtin_amdgcn_mfma_f32_16x16x32_bf16(kf0, qf0, zero4, 0, 0, 0);
                c = __builtin_amdgcn_mfma_f32_16x16x32_bf16(kf1, qf1, c, 0, 0, 0);
                st[n] = c;
            }
        }

        // ---- in-lane softmax (log2 domain) ----
        float pvv[16];
        float mx = -1e30f;
        #pragma unroll
        for (int n = 0; n < 4; ++n) {
            f32x4 a4 = *(const f32x4*)(ambs + kv0 + n * 16 + lg * 4);
            #pragma unroll
            for (int r = 0; r < 4; ++r) {
                int kvj = kv0 + n * 16 + lg * 4 + r;
                float sv = (kvj > qrow) ? -1e30f : st[n][r] * SCALE2 + a4[r] * LOG2E;
                pvv[n * 4 + r] = sv;
                mx = fmaxf(mx, sv);
            }
        }
        mx = fmaxf(mx, __shfl_xor(mx, 16));
        mx = fmaxf(mx, __shfl_xor(mx, 32));

        float mn = fmaxf(m2, mx);
        float corr = exp2f(m2 - mn);
        m2 = mn;
        float ps = 0.f;
        #pragma unroll
        for (int i = 0; i < 16; ++i) {
            float p = exp2f(pvv[i] - mn);
            pvv[i] = p;
            ps += p;
        }
        ps += __shfl_xor(ps, 16);
        ps += __shfl_xor(ps, 32);
        l2 = l2 * corr + ps;

        // ---- write P (4x b64, chunk-XOR swizzled [16 q][64 kv] tile) ----
        #pragma unroll
        for (int n = 0; n < 4; ++n) {
            u16x4 v;
            v[0] = f2bf(pvv[n * 4 + 0]); v[1] = f2bf(pvv[n * 4 + 1]);
            v[2] = f2bf(pvv[n * 4 + 2]); v[3] = f2bf(pvv[n * 4 + 3]);
            int chunk = 2 * n + (lg >> 1);
            int byteoff = lh * 128 + ((chunk ^ (lh & 7)) << 4) + ((lg & 1) << 3);
            *(u16x4*)((char*)myP + byteoff) = v;
        }

        // ---- O rescale (corr redistributed to O's q rows) ----
        float co[4];
        #pragma unroll
        for (int r = 0; r < 4; ++r)
            co[r] = __shfl(corr, srcbase | (qo + r));
        #pragma unroll
        for (int n = 0; n < 4; ++n)
            #pragma unroll
            for (int r = 0; r < 4; ++r)
                o[n][r] *= co[r];

        // ---- O += P V ----
        const int smaxv = (diag && w < 2) ? 0 : 1;
        #pragma unroll
        for (int s = 0; s < 2; ++s) {
            if (s <= smaxv) {
                int chunk = (4 * s + lg) ^ (lh & 7);
                bf16x8 pf = *(const bf16x8*)((const char*)myP + lh * 128 + (chunk << 4));
                #pragma unroll
                for (int n = 0; n < 4; ++n) {
                    bf16x8 vf = LDSFRAG(Vsb, n * 16 + lh, 4 * s + lg);
                    o[n] = __builtin_amdgcn_mfma_f32_16x16x32_bf16(pf, vf, o[n], 0, 0, 0);
                }
            }
        }
        BAR();   // all reads of buf[cur] done before next prefetch overwrites
    }

    // ---- epilogue: normalize, write out[b][t][h*64+d] ----
    float linv[4];
    #pragma unroll
    for (int r = 0; r < 4; ++r)
        linv[r] = 1.0f / __shfl(l2, srcbase | (qo + r));
    float* ob = out + ((size_t)(b * Tsz + qt * 64 + w * 16 + qo)) * Hsz + h * HDsz + lh;
    #pragma unroll
    for (int r = 0; r < 4; ++r)
        #pragma unroll
        for (int n = 0; n < 4; ++n)
            ob[r * Hsz + n * 16] = o[n][r] * linv[r];
}

extern "C" void kernel_launch(void* const* d_in, const int* in_sizes, int n_in,
                              void* d_out, int out_size, void* d_ws, size_t ws_size,
                              hipStream_t stream) {
    const float* X  = (const float*)d_in[0];
    const float* am = (const float*)d_in[1];
    const float* Wq = (const float*)d_in[2];
    const float* bq = (const float*)d_in[3];
    const float* Wk = (const float*)d_in[4];
    const float* bk = (const float*)d_in[5];
    const float* Wv = (const float*)d_in[6];
    const float* bv = (const float*)d_in[7];
    float* out = (float*)d_out;

    const size_t per = (size_t)8192 * Hsz;
    u16* q_ws  = (u16*)d_ws;
    u16* k_ws  = q_ws + per;
    u16* vt_ws = k_ws + per;

    dim3 g1(64, 18);
    qkv_mfma<<<g1, 256, 0, stream>>>(X, Wq, bq, Wk, bk, Wv, bv, q_ws, k_ws, vt_ws);

    dim3 g2(32, NHsz, 4);
    attn_mfma<<<g2, 256, 0, stream>>>(q_ws, k_ws, vt_ws, am, out);
}

// Round 6
// 163.060 us; speedup vs baseline: 6.9750x; 1.5468x over previous
//
#include <hip/hip_runtime.h>
#include <hip/hip_bf16.h>

#define Tsz 2048
#define Hsz 768
#define NHsz 12
#define HDsz 64

typedef unsigned short u16;
typedef unsigned int u32;
typedef __attribute__((ext_vector_type(8))) short bf16x8;
typedef __attribute__((ext_vector_type(4))) float f32x4;
typedef __attribute__((ext_vector_type(4))) u16 u16x4;

__device__ __forceinline__ u16 f2bf(float f) {   // HW convert (RTNE)
    union { __hip_bfloat16 h; u16 u; } c;
    c.h = __float2bfloat16(f);
    return c.u;
}

__device__ __forceinline__ void glds16(const void* src, void* ldsbase) {
    __builtin_amdgcn_global_load_lds(
        (const __attribute__((address_space(1))) u32*)src,
        (__attribute__((address_space(3))) u32*)ldsbase, 16, 0, 0);
}

#define BAR() do { asm volatile("" ::: "memory"); \
                   __builtin_amdgcn_s_barrier();  \
                   asm volatile("" ::: "memory"); } while (0)

// read a bf16x8 MFMA fragment chunk c (16B units) of row `row` from a
// [rows][64] bf16 LDS tile stored with chunk-XOR swizzle (chunk ^= row&7)
#define LDSFRAG(base, row, c) \
    (*(const bf16x8*)((const char*)(base) + (row)*128 + ((((c) << 4)) ^ (((row) & 7) << 4))))

// ---------------------------------------------------------------------------
// Kernel 1: QKV projection with MFMA.  Y = X @ W^T + b.
// 128x128 tile, BK=64, 4 waves. q,k -> [b][h][t][d]; v -> [b][h][d][t].
// ---------------------------------------------------------------------------
__global__ __launch_bounds__(256) void qkv_mfma(
    const float* __restrict__ X,
    const float* __restrict__ Wq, const float* __restrict__ bq,
    const float* __restrict__ Wk, const float* __restrict__ bk,
    const float* __restrict__ Wv, const float* __restrict__ bv,
    u16* __restrict__ q_ws, u16* __restrict__ k_ws, u16* __restrict__ vt_ws)
{
    const int tid = threadIdx.x;
    const int w = tid >> 6, l = tid & 63, lg = l >> 4, lh = l & 15;
    const int m0 = blockIdx.x * 128;
    const int nb = blockIdx.y;
    const int z = nb / 6;
    const int n0l = (nb % 6) * 128;
    const float* W    = (z == 0) ? Wq : (z == 1) ? Wk : Wv;
    const float* bias = (z == 0) ? bq : (z == 1) ? bk : bv;

    __shared__ __align__(16) u16 Xs[128 * 64];
    __shared__ __align__(16) u16 Ws[128 * 64];

    const int wm = w >> 1, wn = w & 1;

    f32x4 acc[4][4];
    #pragma unroll
    for (int i = 0; i < 4; ++i)
        #pragma unroll
        for (int j = 0; j < 4; ++j)
            acc[i][j] = (f32x4){0.f, 0.f, 0.f, 0.f};

    for (int k0 = 0; k0 < Hsz; k0 += 64) {
        __syncthreads();
        #pragma unroll
        for (int p = 0; p < 4; ++p) {
            int id = tid + p * 256;
            int r = id >> 3, c8 = id & 7;
            int cswz = c8 ^ (r & 7);
            float4 xa = *(const float4*)(X + (size_t)(m0 + r) * Hsz + k0 + c8 * 8);
            float4 xb = *(const float4*)(X + (size_t)(m0 + r) * Hsz + k0 + c8 * 8 + 4);
            bf16x8 xv;
            xv[0] = (short)f2bf(xa.x); xv[1] = (short)f2bf(xa.y);
            xv[2] = (short)f2bf(xa.z); xv[3] = (short)f2bf(xa.w);
            xv[4] = (short)f2bf(xb.x); xv[5] = (short)f2bf(xb.y);
            xv[6] = (short)f2bf(xb.z); xv[7] = (short)f2bf(xb.w);
            *(bf16x8*)((char*)Xs + r * 128 + cswz * 16) = xv;
            float4 wa = *(const float4*)(W + (size_t)(n0l + r) * Hsz + k0 + c8 * 8);
            float4 wb = *(const float4*)(W + (size_t)(n0l + r) * Hsz + k0 + c8 * 8 + 4);
            bf16x8 wv8;
            wv8[0] = (short)f2bf(wa.x); wv8[1] = (short)f2bf(wa.y);
            wv8[2] = (short)f2bf(wa.z); wv8[3] = (short)f2bf(wa.w);
            wv8[4] = (short)f2bf(wb.x); wv8[5] = (short)f2bf(wb.y);
            wv8[6] = (short)f2bf(wb.z); wv8[7] = (short)f2bf(wb.w);
            *(bf16x8*)((char*)Ws + r * 128 + cswz * 16) = wv8;
        }
        __syncthreads();
        #pragma unroll
        for (int s = 0; s < 2; ++s) {
            bf16x8 af[4], bfr[4];
            #pragma unroll
            for (int tq = 0; tq < 4; ++tq) {
                af[tq]  = LDSFRAG(Xs, wm * 64 + tq * 16 + lh, 4 * s + lg);
                bfr[tq] = LDSFRAG(Ws, wn * 64 + tq * 16 + lh, 4 * s + lg);
            }
            #pragma unroll
            for (int mt = 0; mt < 4; ++mt)
                #pragma unroll
                for (int nt = 0; nt < 4; ++nt)
                    acc[mt][nt] = __builtin_amdgcn_mfma_f32_16x16x32_bf16(
                        af[mt], bfr[nt], acc[mt][nt], 0, 0, 0);
        }
    }

    #pragma unroll
    for (int nt = 0; nt < 4; ++nt) {
        int nloc = n0l + wn * 64 + nt * 16 + lh;
        float bval = bias[nloc];
        int hh = nloc >> 6, d = nloc & 63;
        #pragma unroll
        for (int mt = 0; mt < 4; ++mt) {
            #pragma unroll
            for (int r = 0; r < 4; ++r) {
                int m = m0 + wm * 64 + mt * 16 + lg * 4 + r;
                int bb = m >> 11, t = m & 2047;
                u16 val = f2bf(acc[mt][nt][r] + bval);
                size_t bh = (size_t)(bb * NHsz + hh);
                if (z == 0)      q_ws[(bh * Tsz + t) * HDsz + d] = val;
                else if (z == 1) k_ws[(bh * Tsz + t) * HDsz + d] = val;
                else             vt_ws[(bh * HDsz + d) * Tsz + t] = val;
            }
        }
    }
}

// ---------------------------------------------------------------------------
// Kernel 2: causal flash attention. Each block processes TWO Q-tiles
// (qt = 16+x and 15-x) so every block does exactly 33 tile-units -> perfect
// static balance (768 blocks = 3/CU). Swapped QK^T, in-lane softmax,
// defer-rescale (THR=8 in exp2 domain), dbuf K/V with counted vmcnt(4).
// ---------------------------------------------------------------------------
__global__ __launch_bounds__(256) void attn_mfma(
    const u16* __restrict__ q_ws, const u16* __restrict__ k_ws,
    const u16* __restrict__ vt_ws, const float* __restrict__ am,
    float* __restrict__ out)
{
    const int tid = threadIdx.x;
    const int w = tid >> 6, l = tid & 63, lg = l >> 4, lh = l & 15;
    const int bx = blockIdx.x;                 // 0..15
    const int h = blockIdx.y, b = blockIdx.z;
    const int bh = b * NHsz + h;

    const u16* Qb = q_ws + (size_t)bh * Tsz * HDsz;
    const u16* Kb = k_ws + (size_t)bh * Tsz * HDsz;
    const u16* Vb = vt_ws + (size_t)bh * HDsz * Tsz;   // [d][t]
    const float* amb = am + (size_t)b * Tsz;

    __shared__ __align__(16) u16 Ks[2][64 * 64];
    __shared__ __align__(16) u16 Vs[2][64 * 64];       // [d][kv] layout
    __shared__ __align__(16) u16 Ps[4][16 * 64];       // per-wave, swizzled
    __shared__ __align__(16) float ambs[Tsz];

    const float LOG2E  = 1.44269504f;
    const float SCALE2 = 0.125f * 1.44269504f;
    const f32x4 zero4 = {0.f, 0.f, 0.f, 0.f};
    u16* myP = &Ps[w][0];
    const int srcbase = l & 0x30;
    const int qo = lg * 4;

    // ---- stage attention mask (8KB), then pre-scale by LOG2E ----
    #pragma unroll
    for (int i = 0; i < 2; ++i)
        glds16(amb + (size_t)(i * 256 + tid) * 4, ambs + (i * 256 + w * 64) * 4);
    asm volatile("s_waitcnt vmcnt(0)" ::: "memory");
    __syncthreads();
    #pragma unroll
    for (int i = 0; i < 8; ++i) ambs[tid * 8 + i] *= LOG2E;
    __syncthreads();   // lgkmcnt-drained barrier for the in-place scale

    #pragma unroll 1
    for (int ph = 0; ph < 2; ++ph) {
        const int qt = (ph == 0) ? (16 + bx) : (15 - bx);
        const int q0 = qt * 64 + w * 16;
        const int qrow = q0 + lh;

        // stage tile 0 K/V into buffer 0
        #pragma unroll
        for (int p = 0; p < 2; ++p) {
            int id = w * 128 + p * 64 + l;
            int r = id >> 3, c8 = id & 7;
            int cswz = c8 ^ (r & 7);
            glds16(Kb + (size_t)r * HDsz + cswz * 8, &Ks[0][(w * 128 + p * 64) * 8]);
            glds16(Vb + (size_t)r * Tsz + cswz * 8, &Vs[0][(w * 128 + p * 64) * 8]);
        }
        bf16x8 qf0 = *(const bf16x8*)(Qb + (size_t)(q0 + lh) * HDsz + lg * 8);
        bf16x8 qf1 = *(const bf16x8*)(Qb + (size_t)(q0 + lh) * HDsz + lg * 8 + 32);
        asm volatile("s_waitcnt vmcnt(0)" ::: "memory");
        BAR();

        f32x4 o[4];
        #pragma unroll
        for (int n = 0; n < 4; ++n) o[n] = zero4;
        float m2 = -1e30f, l2 = 0.f;

        #pragma unroll 1
        for (int kt = 0; kt <= qt; ++kt) {
            const int cur = kt & 1;
            const int kv0 = kt * 64;

            if (kt < qt) {
                const int kv1 = kv0 + 64;
                #pragma unroll
                for (int p = 0; p < 2; ++p) {
                    int id = w * 128 + p * 64 + l;
                    int r = id >> 3, c8 = id & 7;
                    int cswz = c8 ^ (r & 7);
                    glds16(Kb + (size_t)(kv1 + r) * HDsz + cswz * 8,
                           &Ks[cur ^ 1][(w * 128 + p * 64) * 8]);
                    glds16(Vb + (size_t)r * Tsz + kv1 + cswz * 8,
                           &Vs[cur ^ 1][(w * 128 + p * 64) * 8]);
                }
                asm volatile("s_waitcnt vmcnt(4)" ::: "memory");
            } else {
                asm volatile("s_waitcnt vmcnt(0)" ::: "memory");
            }
            BAR();   // tile kt fully staged (all waves)

            const u16* Ksb = &Ks[cur][0];
            const u16* Vsb = &Vs[cur][0];
            const bool diag = (kt == qt);

            // ---- S^T = K @ Q^T : lane holds S[q=lh][kv=kv0+n*16+lg*4+r] ----
            f32x4 st[4];
            __builtin_amdgcn_s_setprio(1);
            if (!diag) {
                #pragma unroll
                for (int n = 0; n < 4; ++n) {
                    int row = n * 16 + lh;
                    bf16x8 kf0 = LDSFRAG(Ksb, row, lg);
                    bf16x8 kf1 = LDSFRAG(Ksb, row, 4 + lg);
                    f32x4 c = __builtin_amdgcn_mfma_f32_16x16x32_bf16(kf0, qf0, zero4, 0, 0, 0);
                    st[n] = __builtin_amdgcn_mfma_f32_16x16x32_bf16(kf1, qf1, c, 0, 0, 0);
                }
            } else {
                #pragma unroll
                for (int n = 0; n < 4; ++n) {
                    st[n] = zero4;
                    if (n <= w) {
                        int row = n * 16 + lh;
                        bf16x8 kf0 = LDSFRAG(Ksb, row, lg);
                        bf16x8 kf1 = LDSFRAG(Ksb, row, 4 + lg);
                        f32x4 c = __builtin_amdgcn_mfma_f32_16x16x32_bf16(kf0, qf0, zero4, 0, 0, 0);
                        st[n] = __builtin_amdgcn_mfma_f32_16x16x32_bf16(kf1, qf1, c, 0, 0, 0);
                    }
                }
            }
            __builtin_amdgcn_s_setprio(0);

            // ---- in-lane softmax (log2 domain) ----
            float pvv[16];
            float mx = -1e30f;
            if (!diag) {
                #pragma unroll
                for (int n = 0; n < 4; ++n) {
                    f32x4 a4 = *(const f32x4*)(ambs + kv0 + n * 16 + lg * 4);
                    #pragma unroll
                    for (int r = 0; r < 4; ++r) {
                        float sv = fmaf(st[n][r], SCALE2, a4[r]);
                        pvv[n * 4 + r] = sv;
                        mx = fmaxf(mx, sv);
                    }
                }
            } else {
                #pragma unroll
                for (int n = 0; n < 4; ++n) {
                    f32x4 a4 = *(const f32x4*)(ambs + kv0 + n * 16 + lg * 4);
                    #pragma unroll
                    for (int r = 0; r < 4; ++r) {
                        int kvj = kv0 + n * 16 + lg * 4 + r;
                        float sv = (kvj > qrow) ? -1e30f : fmaf(st[n][r], SCALE2, a4[r]);
                        pvv[n * 4 + r] = sv;
                        mx = fmaxf(mx, sv);
                    }
                }
            }
            mx = fmaxf(mx, __shfl_xor(mx, 16));
            mx = fmaxf(mx, __shfl_xor(mx, 32));

            // ---- defer-rescale (T13, THR=8 in exp2 domain) ----
            const bool norescale = __all(mx <= m2 + 8.0f);
            float mn = m2;
            if (!norescale) mn = fmaxf(m2, mx);

            float ps = 0.f;
            #pragma unroll
            for (int i = 0; i < 16; ++i) {
                float p = exp2f(pvv[i] - mn);
                pvv[i] = p;
                ps += p;
            }
            ps += __shfl_xor(ps, 16);
            ps += __shfl_xor(ps, 32);

            if (norescale) {
                l2 += ps;
            } else {
                float corr = exp2f(m2 - mn);
                m2 = mn;
                l2 = l2 * corr + ps;
                float co[4];
                #pragma unroll
                for (int r = 0; r < 4; ++r)
                    co[r] = __shfl(corr, srcbase | (qo + r));
                #pragma unroll
                for (int n = 0; n < 4; ++n)
                    #pragma unroll
                    for (int r = 0; r < 4; ++r)
                        o[n][r] *= co[r];
            }

            // ---- write P (4x b64, chunk-XOR swizzled [16 q][64 kv]) ----
            #pragma unroll
            for (int n = 0; n < 4; ++n) {
                u16x4 v;
                v[0] = f2bf(pvv[n * 4 + 0]); v[1] = f2bf(pvv[n * 4 + 1]);
                v[2] = f2bf(pvv[n * 4 + 2]); v[3] = f2bf(pvv[n * 4 + 3]);
                int chunk = 2 * n + (lg >> 1);
                int byteoff = lh * 128 + ((chunk ^ (lh & 7)) << 4) + ((lg & 1) << 3);
                *(u16x4*)((char*)myP + byteoff) = v;
            }

            // ---- O += P V ----
            const int smaxv = (diag && w < 2) ? 0 : 1;
            __builtin_amdgcn_s_setprio(1);
            #pragma unroll
            for (int s = 0; s < 2; ++s) {
                if (s <= smaxv) {
                    int chunk = (4 * s + lg) ^ (lh & 7);
                    bf16x8 pf = *(const bf16x8*)((const char*)myP + lh * 128 + (chunk << 4));
                    #pragma unroll
                    for (int n = 0; n < 4; ++n) {
                        bf16x8 vf = LDSFRAG(Vsb, n * 16 + lh, 4 * s + lg);
                        o[n] = __builtin_amdgcn_mfma_f32_16x16x32_bf16(pf, vf, o[n], 0, 0, 0);
                    }
                }
            }
            __builtin_amdgcn_s_setprio(0);
            BAR();   // all reads of buf[cur] done before next prefetch
        }

        // ---- epilogue: normalize, write out[b][t][h*64+d] ----
        float linv[4];
        #pragma unroll
        for (int r = 0; r < 4; ++r)
            linv[r] = 1.0f / __shfl(l2, srcbase | (qo + r));
        float* ob = out + ((size_t)(b * Tsz + q0 + qo)) * Hsz + h * HDsz + lh;
        #pragma unroll
        for (int r = 0; r < 4; ++r)
            #pragma unroll
            for (int n = 0; n < 4; ++n)
                ob[r * Hsz + n * 16] = o[n][r] * linv[r];
    }
}

extern "C" void kernel_launch(void* const* d_in, const int* in_sizes, int n_in,
                              void* d_out, int out_size, void* d_ws, size_t ws_size,
                              hipStream_t stream) {
    const float* X  = (const float*)d_in[0];
    const float* am = (const float*)d_in[1];
    const float* Wq = (const float*)d_in[2];
    const float* bq = (const float*)d_in[3];
    const float* Wk = (const float*)d_in[4];
    const float* bk = (const float*)d_in[5];
    const float* Wv = (const float*)d_in[6];
    const float* bv = (const float*)d_in[7];
    float* out = (float*)d_out;

    const size_t per = (size_t)8192 * Hsz;
    u16* q_ws  = (u16*)d_ws;
    u16* k_ws  = q_ws + per;
    u16* vt_ws = k_ws + per;

    dim3 g1(64, 18);
    qkv_mfma<<<g1, 256, 0, stream>>>(X, Wq, bq, Wk, bk, Wv, bv, q_ws, k_ws, vt_ws);

    dim3 g2(16, NHsz, 4);
    attn_mfma<<<g2, 256, 0, stream>>>(q_ws, k_ws, vt_ws, am, out);
}

// Round 7
// 150.283 us; speedup vs baseline: 7.5680x; 1.0850x over previous
//
#include <hip/hip_runtime.h>
#include <hip/hip_bf16.h>

#define Tsz 2048
#define Hsz 768
#define NHsz 12
#define HDsz 64

typedef unsigned short u16;
typedef unsigned int u32;
typedef __attribute__((ext_vector_type(8))) short bf16x8;
typedef __attribute__((ext_vector_type(4))) float f32x4;
typedef __attribute__((ext_vector_type(4))) u16 u16x4;

__device__ __forceinline__ u16 f2bf(float f) {   // HW convert (RTNE)
    union { __hip_bfloat16 h; u16 u; } c;
    c.h = __float2bfloat16(f);
    return c.u;
}

__device__ __forceinline__ void glds16(const void* src, void* ldsbase) {
    __builtin_amdgcn_global_load_lds(
        (const __attribute__((address_space(1))) u32*)src,
        (__attribute__((address_space(3))) u32*)ldsbase, 16, 0, 0);
}

#define BAR() do { asm volatile("" ::: "memory"); \
                   __builtin_amdgcn_s_barrier();  \
                   asm volatile("" ::: "memory"); } while (0)

// read a bf16x8 MFMA fragment chunk c (16B units) of row `row` from a
// [rows][64] bf16 LDS tile stored with chunk-XOR swizzle (chunk ^= row&7)
#define LDSFRAG(base, row, c) \
    (*(const bf16x8*)((const char*)(base) + (row)*128 + ((((c) << 4)) ^ (((row) & 7) << 4))))

// ---------------------------------------------------------------------------
// Kernel 0: fp32 -> bf16 conversion of X and Wq/Wk/Wv.
// 32 floats per thread. X: blocks 0..767; W: blocks 768..983 (72 per W).
// ---------------------------------------------------------------------------
__global__ __launch_bounds__(256) void to_bf16(
    const float* __restrict__ X,
    const float* __restrict__ Wq, const float* __restrict__ Wk,
    const float* __restrict__ Wv,
    u16* __restrict__ xb, u16* __restrict__ wb)
{
    const int bx = blockIdx.x, tid = threadIdx.x;
    const float* src;
    u16* dst;
    size_t off;
    if (bx < 768) {
        src = X; dst = xb;
        off = ((size_t)bx * 256 + tid) * 32;
    } else {
        int r = bx - 768;
        int wsel = r / 72, lr = r % 72;
        src = (wsel == 0) ? Wq : (wsel == 1) ? Wk : Wv;
        dst = wb + (size_t)wsel * (Hsz * Hsz);
        off = ((size_t)lr * 256 + tid) * 32;
    }
    #pragma unroll
    for (int c = 0; c < 4; ++c) {
        float4 a = *(const float4*)(src + off + c * 8);
        float4 b = *(const float4*)(src + off + c * 8 + 4);
        bf16x8 v;
        v[0] = (short)f2bf(a.x); v[1] = (short)f2bf(a.y);
        v[2] = (short)f2bf(a.z); v[3] = (short)f2bf(a.w);
        v[4] = (short)f2bf(b.x); v[5] = (short)f2bf(b.y);
        v[6] = (short)f2bf(b.z); v[7] = (short)f2bf(b.w);
        *(bf16x8*)(dst + off + c * 8) = v;
    }
}

// ---------------------------------------------------------------------------
// Kernel 1: QKV projection, bf16 inputs, glds16 dbuf pipeline.
// 128x128 tile, BK=64, 4 waves (64x64 each). Counted vmcnt(8) prefetch.
// q,k -> [b][h][t][d]; v -> [b][h][d][t] (transposed).
// ---------------------------------------------------------------------------
__global__ __launch_bounds__(256) void qkv_gemm(
    const u16* __restrict__ xb, const u16* __restrict__ wb,
    const float* __restrict__ bq, const float* __restrict__ bk,
    const float* __restrict__ bv,
    u16* __restrict__ q_ws, u16* __restrict__ k_ws, u16* __restrict__ vt_ws)
{
    const int tid = threadIdx.x;
    const int w = tid >> 6, l = tid & 63, lg = l >> 4, lh = l & 15;
    const int nb = blockIdx.x;            // 0..17 (n fastest: X-panel reuse)
    const int m0 = blockIdx.y * 128;
    const int z = nb / 6;
    const int n0l = (nb % 6) * 128;
    const u16* Wb = wb + (size_t)z * (Hsz * Hsz);
    const float* bias = (z == 0) ? bq : (z == 1) ? bk : bv;

    __shared__ __align__(16) u16 Xs[2][128 * 64];
    __shared__ __align__(16) u16 Ws[2][128 * 64];

    const int wm = w >> 1, wn = w & 1;

    f32x4 acc[4][4];
    #pragma unroll
    for (int i = 0; i < 4; ++i)
        #pragma unroll
        for (int j = 0; j < 4; ++j)
            acc[i][j] = (f32x4){0.f, 0.f, 0.f, 0.f};

    auto stage = [&](int buf, int k0) {
        #pragma unroll
        for (int p = 0; p < 4; ++p) {
            int id = w * 256 + p * 64 + l;     // chunk 0..1023
            int r = id >> 3, c8 = id & 7;
            int cswz = c8 ^ (r & 7);
            glds16(xb + (size_t)(m0 + r) * Hsz + k0 + cswz * 8,
                   &Xs[buf][(w * 256 + p * 64) * 8]);
            glds16(Wb + (size_t)(n0l + r) * Hsz + k0 + cswz * 8,
                   &Ws[buf][(w * 256 + p * 64) * 8]);
        }
    };

    stage(0, 0);
    asm volatile("s_waitcnt vmcnt(0)" ::: "memory");
    BAR();

    #pragma unroll 1
    for (int ks = 0; ks < 12; ++ks) {
        const int cur = ks & 1;
        if (ks < 11) {
            stage(cur ^ 1, (ks + 1) * 64);
            asm volatile("s_waitcnt vmcnt(8)" ::: "memory");
        } else {
            asm volatile("s_waitcnt vmcnt(0)" ::: "memory");
        }
        BAR();   // tile ks staged, all waves

        __builtin_amdgcn_s_setprio(1);
        #pragma unroll
        for (int s = 0; s < 2; ++s) {
            bf16x8 af[4], bfr[4];
            #pragma unroll
            for (int tq = 0; tq < 4; ++tq) {
                af[tq]  = LDSFRAG(Xs[cur], wm * 64 + tq * 16 + lh, 4 * s + lg);
                bfr[tq] = LDSFRAG(Ws[cur], wn * 64 + tq * 16 + lh, 4 * s + lg);
            }
            #pragma unroll
            for (int mt = 0; mt < 4; ++mt)
                #pragma unroll
                for (int nt = 0; nt < 4; ++nt)
                    acc[mt][nt] = __builtin_amdgcn_mfma_f32_16x16x32_bf16(
                        af[mt], bfr[nt], acc[mt][nt], 0, 0, 0);
        }
        __builtin_amdgcn_s_setprio(0);
        BAR();   // LDS reads done before next stage overwrites
    }

    #pragma unroll
    for (int nt = 0; nt < 4; ++nt) {
        int nloc = n0l + wn * 64 + nt * 16 + lh;
        float bval = bias[nloc];
        int hh = nloc >> 6, d = nloc & 63;
        #pragma unroll
        for (int mt = 0; mt < 4; ++mt) {
            #pragma unroll
            for (int r = 0; r < 4; ++r) {
                int m = m0 + wm * 64 + mt * 16 + lg * 4 + r;
                int bb = m >> 11, t = m & 2047;
                u16 val = f2bf(acc[mt][nt][r] + bval);
                size_t bh = (size_t)(bb * NHsz + hh);
                if (z == 0)      q_ws[(bh * Tsz + t) * HDsz + d] = val;
                else if (z == 1) k_ws[(bh * Tsz + t) * HDsz + d] = val;
                else             vt_ws[(bh * HDsz + d) * Tsz + t] = val;
            }
        }
    }
}

// ---------------------------------------------------------------------------
// Kernel 2: causal flash attention (unchanged from round 6).
// Two Q-tiles per block (16+x, 15-x) -> perfect static balance.
// Swapped QK^T, in-lane softmax, defer-rescale, dbuf K/V, counted vmcnt(4).
// ---------------------------------------------------------------------------
__global__ __launch_bounds__(256) void attn_mfma(
    const u16* __restrict__ q_ws, const u16* __restrict__ k_ws,
    const u16* __restrict__ vt_ws, const float* __restrict__ am,
    float* __restrict__ out)
{
    const int tid = threadIdx.x;
    const int w = tid >> 6, l = tid & 63, lg = l >> 4, lh = l & 15;
    const int bx = blockIdx.x;                 // 0..15
    const int h = blockIdx.y, b = blockIdx.z;
    const int bh = b * NHsz + h;

    const u16* Qb = q_ws + (size_t)bh * Tsz * HDsz;
    const u16* Kb = k_ws + (size_t)bh * Tsz * HDsz;
    const u16* Vb = vt_ws + (size_t)bh * HDsz * Tsz;   // [d][t]
    const float* amb = am + (size_t)b * Tsz;

    __shared__ __align__(16) u16 Ks[2][64 * 64];
    __shared__ __align__(16) u16 Vs[2][64 * 64];       // [d][kv] layout
    __shared__ __align__(16) u16 Ps[4][16 * 64];       // per-wave, swizzled
    __shared__ __align__(16) float ambs[Tsz];

    const float LOG2E  = 1.44269504f;
    const float SCALE2 = 0.125f * 1.44269504f;
    const f32x4 zero4 = {0.f, 0.f, 0.f, 0.f};
    u16* myP = &Ps[w][0];
    const int srcbase = l & 0x30;
    const int qo = lg * 4;

    // ---- stage attention mask (8KB), then pre-scale by LOG2E ----
    #pragma unroll
    for (int i = 0; i < 2; ++i)
        glds16(amb + (size_t)(i * 256 + tid) * 4, ambs + (i * 256 + w * 64) * 4);
    asm volatile("s_waitcnt vmcnt(0)" ::: "memory");
    __syncthreads();
    #pragma unroll
    for (int i = 0; i < 8; ++i) ambs[tid * 8 + i] *= LOG2E;
    __syncthreads();

    #pragma unroll 1
    for (int ph = 0; ph < 2; ++ph) {
        const int qt = (ph == 0) ? (16 + bx) : (15 - bx);
        const int q0 = qt * 64 + w * 16;
        const int qrow = q0 + lh;

        #pragma unroll
        for (int p = 0; p < 2; ++p) {
            int id = w * 128 + p * 64 + l;
            int r = id >> 3, c8 = id & 7;
            int cswz = c8 ^ (r & 7);
            glds16(Kb + (size_t)r * HDsz + cswz * 8, &Ks[0][(w * 128 + p * 64) * 8]);
            glds16(Vb + (size_t)r * Tsz + cswz * 8, &Vs[0][(w * 128 + p * 64) * 8]);
        }
        bf16x8 qf0 = *(const bf16x8*)(Qb + (size_t)(q0 + lh) * HDsz + lg * 8);
        bf16x8 qf1 = *(const bf16x8*)(Qb + (size_t)(q0 + lh) * HDsz + lg * 8 + 32);
        asm volatile("s_waitcnt vmcnt(0)" ::: "memory");
        BAR();

        f32x4 o[4];
        #pragma unroll
        for (int n = 0; n < 4; ++n) o[n] = zero4;
        float m2 = -1e30f, l2 = 0.f;

        #pragma unroll 1
        for (int kt = 0; kt <= qt; ++kt) {
            const int cur = kt & 1;
            const int kv0 = kt * 64;

            if (kt < qt) {
                const int kv1 = kv0 + 64;
                #pragma unroll
                for (int p = 0; p < 2; ++p) {
                    int id = w * 128 + p * 64 + l;
                    int r = id >> 3, c8 = id & 7;
                    int cswz = c8 ^ (r & 7);
                    glds16(Kb + (size_t)(kv1 + r) * HDsz + cswz * 8,
                           &Ks[cur ^ 1][(w * 128 + p * 64) * 8]);
                    glds16(Vb + (size_t)r * Tsz + kv1 + cswz * 8,
                           &Vs[cur ^ 1][(w * 128 + p * 64) * 8]);
                }
                asm volatile("s_waitcnt vmcnt(4)" ::: "memory");
            } else {
                asm volatile("s_waitcnt vmcnt(0)" ::: "memory");
            }
            BAR();

            const u16* Ksb = &Ks[cur][0];
            const u16* Vsb = &Vs[cur][0];
            const bool diag = (kt == qt);

            // ---- S^T = K @ Q^T ----
            f32x4 st[4];
            __builtin_amdgcn_s_setprio(1);
            if (!diag) {
                #pragma unroll
                for (int n = 0; n < 4; ++n) {
                    int row = n * 16 + lh;
                    bf16x8 kf0 = LDSFRAG(Ksb, row, lg);
                    bf16x8 kf1 = LDSFRAG(Ksb, row, 4 + lg);
                    f32x4 c = __builtin_amdgcn_mfma_f32_16x16x32_bf16(kf0, qf0, zero4, 0, 0, 0);
                    st[n] = __builtin_amdgcn_mfma_f32_16x16x32_bf16(kf1, qf1, c, 0, 0, 0);
                }
            } else {
                #pragma unroll
                for (int n = 0; n < 4; ++n) {
                    st[n] = zero4;
                    if (n <= w) {
                        int row = n * 16 + lh;
                        bf16x8 kf0 = LDSFRAG(Ksb, row, lg);
                        bf16x8 kf1 = LDSFRAG(Ksb, row, 4 + lg);
                        f32x4 c = __builtin_amdgcn_mfma_f32_16x16x32_bf16(kf0, qf0, zero4, 0, 0, 0);
                        st[n] = __builtin_amdgcn_mfma_f32_16x16x32_bf16(kf1, qf1, c, 0, 0, 0);
                    }
                }
            }
            __builtin_amdgcn_s_setprio(0);

            // ---- in-lane softmax (log2 domain) ----
            float pvv[16];
            float mx = -1e30f;
            if (!diag) {
                #pragma unroll
                for (int n = 0; n < 4; ++n) {
                    f32x4 a4 = *(const f32x4*)(ambs + kv0 + n * 16 + lg * 4);
                    #pragma unroll
                    for (int r = 0; r < 4; ++r) {
                        float sv = fmaf(st[n][r], SCALE2, a4[r]);
                        pvv[n * 4 + r] = sv;
                        mx = fmaxf(mx, sv);
                    }
                }
            } else {
                #pragma unroll
                for (int n = 0; n < 4; ++n) {
                    f32x4 a4 = *(const f32x4*)(ambs + kv0 + n * 16 + lg * 4);
                    #pragma unroll
                    for (int r = 0; r < 4; ++r) {
                        int kvj = kv0 + n * 16 + lg * 4 + r;
                        float sv = (kvj > qrow) ? -1e30f : fmaf(st[n][r], SCALE2, a4[r]);
                        pvv[n * 4 + r] = sv;
                        mx = fmaxf(mx, sv);
                    }
                }
            }
            mx = fmaxf(mx, __shfl_xor(mx, 16));
            mx = fmaxf(mx, __shfl_xor(mx, 32));

            // ---- defer-rescale (T13) ----
            const bool norescale = __all(mx <= m2 + 8.0f);
            float mn = m2;
            if (!norescale) mn = fmaxf(m2, mx);

            float ps = 0.f;
            #pragma unroll
            for (int i = 0; i < 16; ++i) {
                float p = exp2f(pvv[i] - mn);
                pvv[i] = p;
                ps += p;
            }
            ps += __shfl_xor(ps, 16);
            ps += __shfl_xor(ps, 32);

            if (norescale) {
                l2 += ps;
            } else {
                float corr = exp2f(m2 - mn);
                m2 = mn;
                l2 = l2 * corr + ps;
                float co[4];
                #pragma unroll
                for (int r = 0; r < 4; ++r)
                    co[r] = __shfl(corr, srcbase | (qo + r));
                #pragma unroll
                for (int n = 0; n < 4; ++n)
                    #pragma unroll
                    for (int r = 0; r < 4; ++r)
                        o[n][r] *= co[r];
            }

            // ---- write P ----
            #pragma unroll
            for (int n = 0; n < 4; ++n) {
                u16x4 v;
                v[0] = f2bf(pvv[n * 4 + 0]); v[1] = f2bf(pvv[n * 4 + 1]);
                v[2] = f2bf(pvv[n * 4 + 2]); v[3] = f2bf(pvv[n * 4 + 3]);
                int chunk = 2 * n + (lg >> 1);
                int byteoff = lh * 128 + ((chunk ^ (lh & 7)) << 4) + ((lg & 1) << 3);
                *(u16x4*)((char*)myP + byteoff) = v;
            }

            // ---- O += P V ----
            const int smaxv = (diag && w < 2) ? 0 : 1;
            __builtin_amdgcn_s_setprio(1);
            #pragma unroll
            for (int s = 0; s < 2; ++s) {
                if (s <= smaxv) {
                    int chunk = (4 * s + lg) ^ (lh & 7);
                    bf16x8 pf = *(const bf16x8*)((const char*)myP + lh * 128 + (chunk << 4));
                    #pragma unroll
                    for (int n = 0; n < 4; ++n) {
                        bf16x8 vf = LDSFRAG(Vsb, n * 16 + lh, 4 * s + lg);
                        o[n] = __builtin_amdgcn_mfma_f32_16x16x32_bf16(pf, vf, o[n], 0, 0, 0);
                    }
                }
            }
            __builtin_amdgcn_s_setprio(0);
            BAR();
        }

        // ---- epilogue ----
        float linv[4];
        #pragma unroll
        for (int r = 0; r < 4; ++r)
            linv[r] = 1.0f / __shfl(l2, srcbase | (qo + r));
        float* ob = out + ((size_t)(b * Tsz + q0 + qo)) * Hsz + h * HDsz + lh;
        #pragma unroll
        for (int r = 0; r < 4; ++r)
            #pragma unroll
            for (int n = 0; n < 4; ++n)
                ob[r * Hsz + n * 16] = o[n][r] * linv[r];
    }
}

extern "C" void kernel_launch(void* const* d_in, const int* in_sizes, int n_in,
                              void* d_out, int out_size, void* d_ws, size_t ws_size,
                              hipStream_t stream) {
    const float* X  = (const float*)d_in[0];
    const float* am = (const float*)d_in[1];
    const float* Wq = (const float*)d_in[2];
    const float* bq = (const float*)d_in[3];
    const float* Wk = (const float*)d_in[4];
    const float* bk = (const float*)d_in[5];
    const float* Wv = (const float*)d_in[6];
    const float* bv = (const float*)d_in[7];
    float* out = (float*)d_out;

    const size_t per = (size_t)8192 * Hsz;   // 6,291,456 elems
    u16* q_ws  = (u16*)d_ws;
    u16* k_ws  = q_ws + per;
    u16* vt_ws = k_ws + per;

    // bf16 X and W live in d_out (dead before attn overwrites it):
    // xb 12.6MB + wb 3.5MB <= 25.2MB
    u16* xb = (u16*)d_out;
    u16* wb = xb + per;

    to_bf16<<<dim3(984), 256, 0, stream>>>(X, Wq, Wk, Wv, xb, wb);

    dim3 g1(18, 64);   // n fastest: consecutive blocks share X panel; W L2-resident
    qkv_gemm<<<g1, 256, 0, stream>>>(xb, wb, bq, bk, bv, q_ws, k_ws, vt_ws);

    dim3 g2(16, NHsz, 4);
    attn_mfma<<<g2, 256, 0, stream>>>(q_ws, k_ws, vt_ws, am, out);
}